// Round 11
// baseline (144.516 us; speedup 1.0000x reference)
//
#include <hip/hip_runtime.h>

#define A_N   256
#define T_TOK 32
#define B_N   256
#define V_FRM 16
#define D_DIM 512
#define K_LOG2E 144.269504089f   // TAU * log2(e), TAU = 100

typedef _Float16 half8 __attribute__((ext_vector_type(8)));
typedef _Float16 half4v __attribute__((ext_vector_type(4)));
typedef float    floatx4 __attribute__((ext_vector_type(4)));

__device__ __forceinline__ float fast_exp2(float x) {
#if __has_builtin(__builtin_amdgcn_exp2f)
  return __builtin_amdgcn_exp2f(x);
#else
  return exp2f(x);
#endif
}
__device__ __forceinline__ float fast_rcp(float x) {
#if __has_builtin(__builtin_amdgcn_rcpf)
  return __builtin_amdgcn_rcpf(x);
#else
  return 1.0f / x;
#endif
}

// ---- DPP helpers (VALU pipe) ----
template<int CTRL, int RMASK>
__device__ __forceinline__ float dpp_add(float x) {
  int t = __builtin_amdgcn_update_dpp(0, __float_as_int(x), CTRL, RMASK, 0xf, false);
  return x + __int_as_float(t);
}
// All-lane sum over each 16-lane row via row_ror butterfly (wraps in-row, all
// lanes end with the row total). ctrl row_ror:N = 0x120|N.
__device__ __forceinline__ float rowsum16(float x) {
  x = dpp_add<0x128, 0xf>(x);  // row_ror:8
  x = dpp_add<0x124, 0xf>(x);  // row_ror:4
  x = dpp_add<0x122, 0xf>(x);  // row_ror:2
  x = dpp_add<0x121, 0xf>(x);  // row_ror:1
  return x;
}
// Sum across the 4 quads (lanes colL, colL+16, colL+32, colL+48).
__device__ __forceinline__ float quadsum(float x) {
  x += __shfl_xor(x, 16);
  x += __shfl_xor(x, 32);
  return x;
}

// async global->LDS, 16B/lane. LDS dest = wave-uniform base + lane*16.
__device__ __forceinline__ void async_copy16(const void* g, void* l) {
#if __has_builtin(__builtin_amdgcn_global_load_lds)
  __builtin_amdgcn_global_load_lds((const __attribute__((address_space(1))) void*)g,
                                   (__attribute__((address_space(3))) void*)l, 16, 0, 0);
#else
  const int lane = threadIdx.x & 63;
  *(float4*)((char*)l + lane * 16) = *(const float4*)g;
#endif
}

// ---------------- Kernel 1: L2-normalize rows + cast to fp16 ----------------
// 16-lane group per row, 16 rows per block. text_mask folded in (r6):
// masked text rows are written as exact zeros.
__global__ __launch_bounds__(256) void norm_cast_kernel(
    const float* __restrict__ text, const float* __restrict__ video,
    const float* __restrict__ tmask, _Float16* __restrict__ H)
{
  const int g   = threadIdx.x >> 4;
  const int l   = threadIdx.x & 15;
  const int rid = blockIdx.x * 16 + g;   // 0..12287
  const bool isText = rid < A_N * T_TOK;
  const float* src = isText
                       ? (text + (size_t)rid * D_DIM)
                       : (video + (size_t)(rid - A_N * T_TOK) * D_DIM);
  float4 c[8];
#pragma unroll
  for (int k = 0; k < 8; ++k) c[k] = *(const float4*)(src + k * 64 + l * 4);
  float s0 = 0.f, s1 = 0.f;
#pragma unroll
  for (int k = 0; k < 8; k += 2) {
    s0 += c[k].x * c[k].x + c[k].y * c[k].y + c[k].z * c[k].z + c[k].w * c[k].w;
    s1 += c[k+1].x * c[k+1].x + c[k+1].y * c[k+1].y + c[k+1].z * c[k+1].z + c[k+1].w * c[k+1].w;
  }
  float ss = s0 + s1;
#pragma unroll
  for (int d = 1; d < 16; d <<= 1) ss += __shfl_xor(ss, d);
  float s = 1.0f / fmaxf(sqrtf(ss), 1e-6f);
  if (isText) s *= tmask[rid];    // mask is exactly 0.0 or 1.0
  _Float16* dst = H + (size_t)rid * D_DIM;
#pragma unroll
  for (int k = 0; k < 8; ++k) {
    half4v h;
    h[0] = (_Float16)(c[k].x * s); h[1] = (_Float16)(c[k].y * s);
    h[2] = (_Float16)(c[k].z * s); h[3] = (_Float16)(c[k].w * s);
    *(half4v*)(dst + k * 64 + l * 4) = h;
  }
}

// ---------------- Kernel 2: fused GEMM + dual softmax pooling ----------------
// K-loop: exact r6 structure (best measured 50.2 us): 128x128 block, 64x64
// wave tiles, triple-buffered counted-vmcnt staging, XOR-swizzled glds.
// Round 11 change: MFMA operands SWAPPED -- acc[i][j] = mfma(vid[i], txt[j])
// puts C col = text token t (colL), row = video frame v (quad*4+reg). Both
// softmax trees then decompose in REGISTERS:
//   t2v (over 16 v):  4 regs local + xor16/xor32 cross-quad
//   v2t (over 32 t):  j-pair local + 16-lane DPP row_ror sum (VALU)
//   level-2s:         local + rowsum16 / quadsum
// The entire LDS epilogue (X buffer write, 32 ds_read_b32 + 8 ds_read_b128
// per thread per it, 4 barriers, 524K residual bank-conflict cycles) is
// deleted. exp2 is computed ONCE per logit and shared by both phases:
// phase-B's masked weight is (x!=0 ? E : 0), and x*E is phase-shared since
// masked x==0 contributes 0 to both weighted sums.
// r10's XCD swizzle reverted (rocprof showed it neutral-to-harmful).
__global__ __launch_bounds__(256, 3) void score_kernel(
    const _Float16* __restrict__ H, float* __restrict__ out)
{
  // 3 GEMM staging buffers of 16 KB (sA 8K + sB 8K each). No epilogue LDS.
  __shared__ __align__(16) char smem[49152];

  const int tid  = threadIdx.x;
  const int w    = tid >> 6;
  const int lane = tid & 63;
  const int bn   = blockIdx.x;       // 0..31 -> 8 b's (128 video rows)
  const int bm   = blockIdx.y;       // 0..63 -> 4 a's (128 text rows)
  const int mBase = bm * 128;
  const int nBase = bn * 128;

  const char* gA = (const char*)(H + (size_t)mBase * D_DIM);
  const char* gB = (const char*)(H + (size_t)(A_N * T_TOK + nBase) * D_DIM);
  // Swizzled source (r1, verified): lane l stages row rbase+(l>>2), 16B chunk
  // ((l&3) ^ ((l>>3)&3)); LDS slot (row, c) holds global chunk c ^ ((row>>1)&3).
  const int rowoff = (lane >> 2) * 1024 + (((lane & 3) ^ ((lane >> 3) & 3)) * 16);
  const int rbase0 = w * 32;
  const int rbase1 = w * 32 + 16;

  char* bufA = smem;            // compute buffer (tile kt)
  char* bufB = smem + 16384;    // next (tile kt+1)
  char* bufC = smem + 32768;    // staging target (tile kt+2)

  // prologue: stage tile 0 -> bufA, tile 1 -> bufB (8 loads outstanding)
  async_copy16(gA + (size_t)rbase0 * 1024 + rowoff,        bufA + rbase0 * 64);
  async_copy16(gB + (size_t)rbase0 * 1024 + rowoff,        bufA + 8192 + rbase0 * 64);
  async_copy16(gA + (size_t)rbase1 * 1024 + rowoff,        bufA + rbase1 * 64);
  async_copy16(gB + (size_t)rbase1 * 1024 + rowoff,        bufA + 8192 + rbase1 * 64);
  async_copy16(gA + (size_t)rbase0 * 1024 + rowoff + 64,   bufB + rbase0 * 64);
  async_copy16(gB + (size_t)rbase0 * 1024 + rowoff + 64,   bufB + 8192 + rbase0 * 64);
  async_copy16(gA + (size_t)rbase1 * 1024 + rowoff + 64,   bufB + rbase1 * 64);
  async_copy16(gB + (size_t)rbase1 * 1024 + rowoff + 64,   bufB + 8192 + rbase1 * 64);

  // acc[i][j]: i = VIDEO tile (M operand), j = TEXT tile (N operand).
  floatx4 acc[4][4];
#pragma unroll
  for (int i = 0; i < 4; ++i)
#pragma unroll
    for (int j = 0; j < 4; ++j) acc[i][j] = {0.f, 0.f, 0.f, 0.f};

  const int colL = lane & 15;
  const int quad = lane >> 4;
  const int vRowBase = (w >> 1) * 64;   // video rows (sB half) for this wave
  const int tRowBase = (w & 1) * 64;    // text rows (sA half) for this wave
  // Read-side swizzle: row = base16 + colL -> (row>>1)&3 == (colL>>1)&3.
  const int quadS = (quad ^ ((colL >> 1) & 3)) * 8;

  // drain tile 0 only (keep tile 1's 4 loads in flight), then barrier
  asm volatile("s_waitcnt vmcnt(4)" ::: "memory");
  __builtin_amdgcn_s_barrier();

  for (int kt = 0; kt < 16; ++kt) {
    // stage tile kt+2 into bufC (stays in flight across this iteration's barrier)
    if (kt < 14) {
      const int kb = (kt + 2) * 64;
      async_copy16(gA + (size_t)rbase0 * 1024 + rowoff + kb, bufC + rbase0 * 64);
      async_copy16(gB + (size_t)rbase0 * 1024 + rowoff + kb, bufC + 8192 + rbase0 * 64);
      async_copy16(gA + (size_t)rbase1 * 1024 + rowoff + kb, bufC + rbase1 * 64);
      async_copy16(gB + (size_t)rbase1 * 1024 + rowoff + kb, bufC + 8192 + rbase1 * 64);
    }

    const _Float16* sA = (const _Float16*)bufA;           // text rows
    const _Float16* sB = (const _Float16*)(bufA + 8192);  // video rows
    half8 vF[4], tF[4];
#pragma unroll
    for (int i = 0; i < 4; ++i)
      vF[i] = *(const half8*)&sB[(vRowBase + i * 16 + colL) * 32 + quadS];
#pragma unroll
    for (int j = 0; j < 4; ++j)
      tF[j] = *(const half8*)&sA[(tRowBase + j * 16 + colL) * 32 + quadS];
    // SWAPPED: video is the M operand, text the N operand.
#pragma unroll
    for (int i = 0; i < 4; ++i)
#pragma unroll
      for (int j = 0; j < 4; ++j)
        acc[i][j] = __builtin_amdgcn_mfma_f32_16x16x32_f16(vF[i], tF[j], acc[i][j], 0, 0, 0);

    // Retire tile kt+1's 4 loads (oldest), keep kt+2's in flight.
    if (kt < 14) asm volatile("s_waitcnt vmcnt(4) lgkmcnt(0)" ::: "memory");
    else         asm volatile("s_waitcnt vmcnt(0) lgkmcnt(0)" ::: "memory");
    __builtin_amdgcn_s_barrier();

    char* t = bufA; bufA = bufB; bufB = bufC; bufC = t;
  }

  // ---- epilogue: fully in registers ----
  // acc[i][j][r] = logit[ b = bn*8 + (w>>1)*4 + i, v = quad*4 + r,
  //                       a = bm*4 + (w&1)*2 + (j>>1), t = (j&1)*16 + colL ]
  float res[4][2];
#pragma unroll
  for (int i = 0; i < 4; ++i) {
    // --- phase A level 1: tva[j] = t2v(a,t,b) -- softmax-weighted over 16 v.
    // E/XE computed once; reused by phase B (shared exp).
    float E[4][4], XE[4][4], tva[4];
#pragma unroll
    for (int j = 0; j < 4; ++j) {
      float pe = 0.f, px = 0.f;
#pragma unroll
      for (int r = 0; r < 4; ++r) {
        const float x = acc[i][j][r];
        const float e = fast_exp2(x * K_LOG2E);
        E[j][r]  = e;
        XE[j][r] = x * e;        // masked x==0 -> 0 exactly
        pe += e; px += XE[j][r];
      }
      pe = quadsum(pe); px = quadsum(px);
      tva[j] = px * fast_rcp(pe);   // exact 0 for masked t (px==0)
    }

#pragma unroll
    for (int a = 0; a < 2; ++a) {
      // --- level-2 A: masked softmax-weighted over 32 t (j-pair + 16 colL)
      const float v0 = (tva[a*2]   != 0.0f) ? tva[a*2]   : -1e30f;
      const float v1 = (tva[a*2+1] != 0.0f) ? tva[a*2+1] : -1e30f;
      const float e0 = fast_exp2(v0 * K_LOG2E);    // -1e30 -> 0
      const float e1 = fast_exp2(v1 * K_LOG2E);
      float seA = e0 + e1;
      float sxA = fmaf(v0, e0, v1 * e1);           // (-1e30)*0 = -0, finite
      seA = rowsum16(seA); sxA = rowsum16(sxA);
      const float t2v = sxA * fast_rcp(seA);

      // --- phase B level 1: v2t[r] over 32 t (j-pair local + 16-lane rowsum)
      float v2t[4];
#pragma unroll
      for (int r = 0; r < 4; ++r) {
        const float x0 = acc[i][a*2][r], x1 = acc[i][a*2+1][r];
        const float m0 = (x0 != 0.0f) ? E[a*2][r]   : 0.0f;   // masked weight
        const float m1 = (x1 != 0.0f) ? E[a*2+1][r] : 0.0f;
        float seB = m0 + m1;
        float sxB = XE[a*2][r] + XE[a*2+1][r];     // masked terms already 0
        seB = rowsum16(seB); sxB = rowsum16(sxB);
        v2t[r] = sxB * fast_rcp(seB);
      }
      // --- level-2 B: over 16 v (4 regs local + cross-quad). No v-masking.
      float se2 = 0.f, sx2 = 0.f;
#pragma unroll
      for (int r = 0; r < 4; ++r) {
        const float e = fast_exp2(v2t[r] * K_LOG2E);
        se2 += e; sx2 = fmaf(v2t[r], e, sx2);
      }
      se2 = quadsum(se2); sx2 = quadsum(sx2);
      const float v2tL2 = sx2 * fast_rcp(se2);

      res[i][a] = 0.5f * (t2v + v2tL2);
    }
  }

  // All reductions were all-lane (rowsum16 / quadsum), so res is uniform
  // across the wave: lane 0 writes its wave's 8 outputs.
  if (lane == 0) {
    const int aBase = bm * 4 + (w & 1) * 2;
    const int bBase = bn * 8 + (w >> 1) * 4;
#pragma unroll
    for (int i = 0; i < 4; ++i)
#pragma unroll
      for (int a = 0; a < 2; ++a)
        out[(size_t)(aBase + a) * B_N + bBase + i] = res[i][a];
  }
}

extern "C" void kernel_launch(void* const* d_in, const int* in_sizes, int n_in,
                              void* d_out, int out_size, void* d_ws, size_t ws_size,
                              hipStream_t stream) {
  const float* text  = (const float*)d_in[0];
  const float* video = (const float*)d_in[1];
  const float* tmask = (const float*)d_in[2];
  float* out = (float*)d_out;
  _Float16* H = (_Float16*)d_ws;

  norm_cast_kernel<<<(A_N * T_TOK + B_N * V_FRM) / 16, 256, 0, stream>>>(text, video, tmask, H);
  score_kernel<<<dim3(B_N * V_FRM / 128, A_N * T_TOK / 128), 256, 0, stream>>>(H, out);
}

// Round 12
// 133.903 us; speedup vs baseline: 1.0793x; 1.0793x over previous
//
#include <hip/hip_runtime.h>

#define A_N   256
#define T_TOK 32
#define B_N   256
#define V_FRM 16
#define D_DIM 512
#define K_LOG2E 144.269504089f   // TAU * log2(e), TAU = 100

typedef _Float16 half8 __attribute__((ext_vector_type(8)));
typedef _Float16 half4v __attribute__((ext_vector_type(4)));
typedef float    floatx4 __attribute__((ext_vector_type(4)));

__device__ __forceinline__ float fast_exp2(float x) {
#if __has_builtin(__builtin_amdgcn_exp2f)
  return __builtin_amdgcn_exp2f(x);
#else
  return exp2f(x);
#endif
}
__device__ __forceinline__ float fast_rcp(float x) {
#if __has_builtin(__builtin_amdgcn_rcpf)
  return __builtin_amdgcn_rcpf(x);
#else
  return 1.0f / x;
#endif
}

// ---- DPP helpers (VALU pipe) ----
template<int CTRL, int RMASK>
__device__ __forceinline__ float dpp_add(float x) {
  int t = __builtin_amdgcn_update_dpp(0, __float_as_int(x), CTRL, RMASK, 0xf, false);
  return x + __int_as_float(t);
}
// All-lane sum over each 16-lane row via row_ror butterfly (wraps in-row, all
// lanes end with the row total). ctrl row_ror:N = 0x120|N.
__device__ __forceinline__ float rowsum16(float x) {
  x = dpp_add<0x128, 0xf>(x);  // row_ror:8
  x = dpp_add<0x124, 0xf>(x);  // row_ror:4
  x = dpp_add<0x122, 0xf>(x);  // row_ror:2
  x = dpp_add<0x121, 0xf>(x);  // row_ror:1
  return x;
}
// Sum across the 4 quads (lanes colL, colL+16, colL+32, colL+48).
__device__ __forceinline__ float quadsum(float x) {
  x += __shfl_xor(x, 16);
  x += __shfl_xor(x, 32);
  return x;
}

// async global->LDS, 16B/lane. LDS dest = wave-uniform base + lane*16.
__device__ __forceinline__ void async_copy16(const void* g, void* l) {
#if __has_builtin(__builtin_amdgcn_global_load_lds)
  __builtin_amdgcn_global_load_lds((const __attribute__((address_space(1))) void*)g,
                                   (__attribute__((address_space(3))) void*)l, 16, 0, 0);
#else
  const int lane = threadIdx.x & 63;
  *(float4*)((char*)l + lane * 16) = *(const float4*)g;
#endif
}

// ---------------- Kernel 1: L2-normalize rows + cast to fp16 ----------------
// 16-lane group per row, 16 rows per block. text_mask folded in (r6):
// masked text rows are written as exact zeros.
__global__ __launch_bounds__(256) void norm_cast_kernel(
    const float* __restrict__ text, const float* __restrict__ video,
    const float* __restrict__ tmask, _Float16* __restrict__ H)
{
  const int g   = threadIdx.x >> 4;
  const int l   = threadIdx.x & 15;
  const int rid = blockIdx.x * 16 + g;   // 0..12287
  const bool isText = rid < A_N * T_TOK;
  const float* src = isText
                       ? (text + (size_t)rid * D_DIM)
                       : (video + (size_t)(rid - A_N * T_TOK) * D_DIM);
  float4 c[8];
#pragma unroll
  for (int k = 0; k < 8; ++k) c[k] = *(const float4*)(src + k * 64 + l * 4);
  float s0 = 0.f, s1 = 0.f;
#pragma unroll
  for (int k = 0; k < 8; k += 2) {
    s0 += c[k].x * c[k].x + c[k].y * c[k].y + c[k].z * c[k].z + c[k].w * c[k].w;
    s1 += c[k+1].x * c[k+1].x + c[k+1].y * c[k+1].y + c[k+1].z * c[k+1].z + c[k+1].w * c[k+1].w;
  }
  float ss = s0 + s1;
#pragma unroll
  for (int d = 1; d < 16; d <<= 1) ss += __shfl_xor(ss, d);
  float s = 1.0f / fmaxf(sqrtf(ss), 1e-6f);
  if (isText) s *= tmask[rid];    // mask is exactly 0.0 or 1.0
  _Float16* dst = H + (size_t)rid * D_DIM;
#pragma unroll
  for (int k = 0; k < 8; ++k) {
    half4v h;
    h[0] = (_Float16)(c[k].x * s); h[1] = (_Float16)(c[k].y * s);
    h[2] = (_Float16)(c[k].z * s); h[3] = (_Float16)(c[k].w * s);
    *(half4v*)(dst + k * 64 + l * 4) = h;
  }
}

// ---------------- Kernel 2: fused GEMM + dual softmax pooling ----------------
// K-loop: exact r6 structure (best measured 50.2 us). Swapped MFMA operands
// (r11, layout verified bit-identical): C col = text token t (colL),
// row = video frame v (quad*4+reg) -> epilogue fully in registers,
// SQ_LDS_BANK_CONFLICT == 0 (verified r11).
// Round 12 fix: r11 spilled (WRITE_SIZE 103 MB) because it CACHED E[4][4] +
// XE[4][4] (32 VGPRs) on top of the 64-reg acc tile. Exp on the
// transcendental pipe is ~4 cyc and the pipe is idle -> RECOMPUTE exp in
// phase B instead of caching. Epilogue processes one (i, a-pair) at a time:
// working set = 8 logits + ~12 temps; acc stays AGPR-resident (as in r6,
// which carried the same 64-reg acc without spilling at VGPR=68).
__global__ __launch_bounds__(256, 3) void score_kernel(
    const _Float16* __restrict__ H, float* __restrict__ out)
{
  // 3 GEMM staging buffers of 16 KB (sA 8K + sB 8K each). No epilogue LDS.
  __shared__ __align__(16) char smem[49152];

  const int tid  = threadIdx.x;
  const int w    = tid >> 6;
  const int lane = tid & 63;
  const int bn   = blockIdx.x;       // 0..31 -> 8 b's (128 video rows)
  const int bm   = blockIdx.y;       // 0..63 -> 4 a's (128 text rows)
  const int mBase = bm * 128;
  const int nBase = bn * 128;

  const char* gA = (const char*)(H + (size_t)mBase * D_DIM);
  const char* gB = (const char*)(H + (size_t)(A_N * T_TOK + nBase) * D_DIM);
  // Swizzled source (r1, verified): lane l stages row rbase+(l>>2), 16B chunk
  // ((l&3) ^ ((l>>3)&3)); LDS slot (row, c) holds global chunk c ^ ((row>>1)&3).
  const int rowoff = (lane >> 2) * 1024 + (((lane & 3) ^ ((lane >> 3) & 3)) * 16);
  const int rbase0 = w * 32;
  const int rbase1 = w * 32 + 16;

  char* bufA = smem;            // compute buffer (tile kt)
  char* bufB = smem + 16384;    // next (tile kt+1)
  char* bufC = smem + 32768;    // staging target (tile kt+2)

  // prologue: stage tile 0 -> bufA, tile 1 -> bufB (8 loads outstanding)
  async_copy16(gA + (size_t)rbase0 * 1024 + rowoff,        bufA + rbase0 * 64);
  async_copy16(gB + (size_t)rbase0 * 1024 + rowoff,        bufA + 8192 + rbase0 * 64);
  async_copy16(gA + (size_t)rbase1 * 1024 + rowoff,        bufA + rbase1 * 64);
  async_copy16(gB + (size_t)rbase1 * 1024 + rowoff,        bufA + 8192 + rbase1 * 64);
  async_copy16(gA + (size_t)rbase0 * 1024 + rowoff + 64,   bufB + rbase0 * 64);
  async_copy16(gB + (size_t)rbase0 * 1024 + rowoff + 64,   bufB + 8192 + rbase0 * 64);
  async_copy16(gA + (size_t)rbase1 * 1024 + rowoff + 64,   bufB + rbase1 * 64);
  async_copy16(gB + (size_t)rbase1 * 1024 + rowoff + 64,   bufB + 8192 + rbase1 * 64);

  // acc[i][j]: i = VIDEO tile (M operand), j = TEXT tile (N operand).
  floatx4 acc[4][4];
#pragma unroll
  for (int i = 0; i < 4; ++i)
#pragma unroll
    for (int j = 0; j < 4; ++j) acc[i][j] = {0.f, 0.f, 0.f, 0.f};

  const int colL = lane & 15;
  const int quad = lane >> 4;
  const int vRowBase = (w >> 1) * 64;   // video rows (sB half) for this wave
  const int tRowBase = (w & 1) * 64;    // text rows (sA half) for this wave
  // Read-side swizzle: row = base16 + colL -> (row>>1)&3 == (colL>>1)&3.
  const int quadS = (quad ^ ((colL >> 1) & 3)) * 8;

  // drain tile 0 only (keep tile 1's 4 loads in flight), then barrier
  asm volatile("s_waitcnt vmcnt(4)" ::: "memory");
  __builtin_amdgcn_s_barrier();

  for (int kt = 0; kt < 16; ++kt) {
    // stage tile kt+2 into bufC (stays in flight across this iteration's barrier)
    if (kt < 14) {
      const int kb = (kt + 2) * 64;
      async_copy16(gA + (size_t)rbase0 * 1024 + rowoff + kb, bufC + rbase0 * 64);
      async_copy16(gB + (size_t)rbase0 * 1024 + rowoff + kb, bufC + 8192 + rbase0 * 64);
      async_copy16(gA + (size_t)rbase1 * 1024 + rowoff + kb, bufC + rbase1 * 64);
      async_copy16(gB + (size_t)rbase1 * 1024 + rowoff + kb, bufC + 8192 + rbase1 * 64);
    }

    const _Float16* sA = (const _Float16*)bufA;           // text rows
    const _Float16* sB = (const _Float16*)(bufA + 8192);  // video rows
    half8 vF[4], tF[4];
#pragma unroll
    for (int i = 0; i < 4; ++i)
      vF[i] = *(const half8*)&sB[(vRowBase + i * 16 + colL) * 32 + quadS];
#pragma unroll
    for (int j = 0; j < 4; ++j)
      tF[j] = *(const half8*)&sA[(tRowBase + j * 16 + colL) * 32 + quadS];
    // SWAPPED: video is the M operand, text the N operand.
#pragma unroll
    for (int i = 0; i < 4; ++i)
#pragma unroll
      for (int j = 0; j < 4; ++j)
        acc[i][j] = __builtin_amdgcn_mfma_f32_16x16x32_f16(vF[i], tF[j], acc[i][j], 0, 0, 0);

    // Retire tile kt+1's 4 loads (oldest), keep kt+2's in flight.
    if (kt < 14) asm volatile("s_waitcnt vmcnt(4) lgkmcnt(0)" ::: "memory");
    else         asm volatile("s_waitcnt vmcnt(0) lgkmcnt(0)" ::: "memory");
    __builtin_amdgcn_s_barrier();

    char* t = bufA; bufA = bufB; bufB = bufC; bufC = t;
  }

  // ---- epilogue: fully in registers, one (i, a-pair) at a time ----
  // acc[i][j][r] = logit[ b = bn*8 + (w>>1)*4 + i, v = quad*4 + r,
  //                       a = bm*4 + (w&1)*2 + (j>>1), t = (j&1)*16 + colL ]
  float res[4][2];
#pragma unroll
  for (int i = 0; i < 4; ++i) {
#pragma unroll
    for (int a = 0; a < 2; ++a) {
      // the 8 logits of this (i, a): x0 = t-half 0, x1 = t-half 1
      float x0[4], x1[4];
#pragma unroll
      for (int r = 0; r < 4; ++r) { x0[r] = acc[i][a*2][r]; x1[r] = acc[i][a*2+1][r]; }

      // --- phase A level 1: tva = t2v(a,t,b), softmax-weighted over 16 v
      float pe0 = 0.f, px0 = 0.f, pe1 = 0.f, px1 = 0.f;
#pragma unroll
      for (int r = 0; r < 4; ++r) {
        const float e0 = fast_exp2(x0[r] * K_LOG2E);
        const float e1 = fast_exp2(x1[r] * K_LOG2E);
        pe0 += e0; px0 = fmaf(x0[r], e0, px0);   // masked x==0 -> e=1, x*e=0
        pe1 += e1; px1 = fmaf(x1[r], e1, px1);
      }
      pe0 = quadsum(pe0); px0 = quadsum(px0);
      pe1 = quadsum(pe1); px1 = quadsum(px1);
      const float tva0 = px0 * fast_rcp(pe0);    // exact 0 for masked t
      const float tva1 = px1 * fast_rcp(pe1);

      // --- level-2 A: masked softmax-weighted over 32 t (t-half pair + 16 colL)
      const float v0 = (tva0 != 0.0f) ? tva0 : -1e30f;
      const float v1 = (tva1 != 0.0f) ? tva1 : -1e30f;
      const float ea0 = fast_exp2(v0 * K_LOG2E);   // -1e30 -> 0
      const float ea1 = fast_exp2(v1 * K_LOG2E);
      float seA = ea0 + ea1;
      float sxA = fmaf(v0, ea0, v1 * ea1);         // (-1e30)*0 = -0, finite
      seA = rowsum16(seA); sxA = rowsum16(sxA);
      const float t2v = sxA * fast_rcp(seA);

      // --- phase B level 1: v2t[r], masked softmax over 32 t (exp RECOMPUTED)
      float v2t[4];
#pragma unroll
      for (int r = 0; r < 4; ++r) {
        const float e0 = fast_exp2(x0[r] * K_LOG2E);
        const float e1 = fast_exp2(x1[r] * K_LOG2E);
        const float m0 = (x0[r] != 0.0f) ? e0 : 0.0f;   // masked weight
        const float m1 = (x1[r] != 0.0f) ? e1 : 0.0f;
        float seB = m0 + m1;
        float sxB = fmaf(x0[r], m0, x1[r] * m1);        // masked terms -> 0
        seB = rowsum16(seB); sxB = rowsum16(sxB);
        v2t[r] = sxB * fast_rcp(seB);
      }

      // --- level-2 B: over 16 v (4 regs local + cross-quad). No v-masking.
      float se2 = 0.f, sx2 = 0.f;
#pragma unroll
      for (int r = 0; r < 4; ++r) {
        const float e = fast_exp2(v2t[r] * K_LOG2E);
        se2 += e; sx2 = fmaf(v2t[r], e, sx2);
      }
      se2 = quadsum(se2); sx2 = quadsum(sx2);
      const float v2tL2 = sx2 * fast_rcp(se2);

      res[i][a] = 0.5f * (t2v + v2tL2);
    }
  }

  // All reductions were all-lane (rowsum16 / quadsum), so res is uniform
  // across the wave: lane 0 writes its wave's 8 outputs.
  if (lane == 0) {
    const int aBase = bm * 4 + (w & 1) * 2;
    const int bBase = bn * 8 + (w >> 1) * 4;
#pragma unroll
    for (int i = 0; i < 4; ++i)
#pragma unroll
      for (int a = 0; a < 2; ++a)
        out[(size_t)(aBase + a) * B_N + bBase + i] = res[i][a];
  }
}

extern "C" void kernel_launch(void* const* d_in, const int* in_sizes, int n_in,
                              void* d_out, int out_size, void* d_ws, size_t ws_size,
                              hipStream_t stream) {
  const float* text  = (const float*)d_in[0];
  const float* video = (const float*)d_in[1];
  const float* tmask = (const float*)d_in[2];
  float* out = (float*)d_out;
  _Float16* H = (_Float16*)d_ws;

  norm_cast_kernel<<<(A_N * T_TOK + B_N * V_FRM) / 16, 256, 0, stream>>>(text, video, tmask, H);
  score_kernel<<<dim3(B_N * V_FRM / 128, A_N * T_TOK / 128), 256, 0, stream>>>(H, out);
}

// Round 13
// 116.484 us; speedup vs baseline: 1.2406x; 1.1495x over previous
//
#include <hip/hip_runtime.h>

#define A_N   256
#define T_TOK 32
#define B_N   256
#define V_FRM 16
#define D_DIM 512
#define K_LOG2E 144.269504089f   // TAU * log2(e), TAU = 100

// Epilogue LDS layout: X[2 rounds][8 pairs][16 v][32 t + 4 pad]
#define TS  36                   // floats per v-row
#define PS  580                  // floats per pair slab (16*36 + 4)
#define REP 4640                 // floats per round slab (8*580)

typedef _Float16 half8 __attribute__((ext_vector_type(8)));
typedef _Float16 half4v __attribute__((ext_vector_type(4)));
typedef float    floatx4 __attribute__((ext_vector_type(4)));

__device__ __forceinline__ float fast_exp2(float x) {
#if __has_builtin(__builtin_amdgcn_exp2f)
  return __builtin_amdgcn_exp2f(x);
#else
  return exp2f(x);
#endif
}
__device__ __forceinline__ float fast_rcp(float x) {
#if __has_builtin(__builtin_amdgcn_rcpf)
  return __builtin_amdgcn_rcpf(x);
#else
  return 1.0f / x;
#endif
}

// ---- DPP reductions: VALU pipe, not LDS (shfl_xor lowers to ds_swizzle) ----
template<int CTRL, int RMASK>
__device__ __forceinline__ float dpp_add(float x) {
  int t = __builtin_amdgcn_update_dpp(0, __float_as_int(x), CTRL, RMASK, 0xf, false);
  return x + __int_as_float(t);
}
// Sum over each 32-lane half; result valid in lane 31 / lane 63 only.
__device__ __forceinline__ float grp32_sum(float x) {
  x = dpp_add<0x111, 0xf>(x);   // row_shr:1
  x = dpp_add<0x112, 0xf>(x);   // row_shr:2
  x = dpp_add<0x114, 0xf>(x);   // row_shr:4
  x = dpp_add<0x118, 0xf>(x);   // row_shr:8  -> lane15 of each row = row sum
  x = dpp_add<0x142, 0xa>(x);   // bcast15 into rows 1,3 -> lane31/63 = 32-sum
  return x;
}
// x + shfl_xor(x,1) on all lanes: quad_perm [1,0,3,2]
__device__ __forceinline__ float pair_sum(float x) {
  return dpp_add<0xB1, 0xf>(x);
}

// No-max exp-sum (r5): inputs are cosine sims, |x| << 0.88 overflow bound at
// K=144.27; masked inputs are -1e30 -> exp2 = 0, (-1e30)*0 = -0 (finite).
// Masked-t rows (all logits exactly 0): e=1 each, sx=0 -> ratio exact 0.
__device__ __forceinline__ void expsum16(const float* x, float& se, float& sx) {
  float s0 = 0.f, s1 = 0.f, x0 = 0.f, x1 = 0.f;
#pragma unroll
  for (int i = 0; i < 16; i += 2) {
    float e0 = fast_exp2(x[i]     * K_LOG2E);
    float e1 = fast_exp2(x[i + 1] * K_LOG2E);
    s0 += e0; s1 += e1;
    x0 = fmaf(x[i], e0, x0); x1 = fmaf(x[i + 1], e1, x1);
  }
  se = s0 + s1; sx = x0 + x1;
}

// async global->LDS, 16B/lane. LDS dest = wave-uniform base + lane*16.
__device__ __forceinline__ void async_copy16(const void* g, void* l) {
#if __has_builtin(__builtin_amdgcn_global_load_lds)
  __builtin_amdgcn_global_load_lds((const __attribute__((address_space(1))) void*)g,
                                   (__attribute__((address_space(3))) void*)l, 16, 0, 0);
#else
  const int lane = threadIdx.x & 63;
  *(float4*)((char*)l + lane * 16) = *(const float4*)g;
#endif
}

// ---------------- Kernel 1: L2-normalize rows + cast to fp16 ----------------
// 16-lane group per row, 16 rows per block. text_mask folded in (r6):
// masked text rows are written as exact zeros, so masked logits come out of
// the GEMM as exact 0 (removes the LM stage + mask-fold in score_kernel).
__global__ __launch_bounds__(256) void norm_cast_kernel(
    const float* __restrict__ text, const float* __restrict__ video,
    const float* __restrict__ tmask, _Float16* __restrict__ H)
{
  const int g   = threadIdx.x >> 4;
  const int l   = threadIdx.x & 15;
  const int rid = blockIdx.x * 16 + g;   // 0..12287
  const bool isText = rid < A_N * T_TOK;
  const float* src = isText
                       ? (text + (size_t)rid * D_DIM)
                       : (video + (size_t)(rid - A_N * T_TOK) * D_DIM);
  float4 c[8];
#pragma unroll
  for (int k = 0; k < 8; ++k) c[k] = *(const float4*)(src + k * 64 + l * 4);
  float s0 = 0.f, s1 = 0.f;
#pragma unroll
  for (int k = 0; k < 8; k += 2) {
    s0 += c[k].x * c[k].x + c[k].y * c[k].y + c[k].z * c[k].z + c[k].w * c[k].w;
    s1 += c[k+1].x * c[k+1].x + c[k+1].y * c[k+1].y + c[k+1].z * c[k+1].z + c[k+1].w * c[k+1].w;
  }
  float ss = s0 + s1;
#pragma unroll
  for (int d = 1; d < 16; d <<= 1) ss += __shfl_xor(ss, d);
  float s = 1.0f / fmaxf(sqrtf(ss), 1e-6f);
  if (isText) s *= tmask[rid];    // mask is exactly 0.0 or 1.0
  _Float16* dst = H + (size_t)rid * D_DIM;
#pragma unroll
  for (int k = 0; k < 8; ++k) {
    half4v h;
    h[0] = (_Float16)(c[k].x * s); h[1] = (_Float16)(c[k].y * s);
    h[2] = (_Float16)(c[k].z * s); h[3] = (_Float16)(c[k].w * s);
    *(half4v*)(dst + k * 64 + l * 4) = h;
  }
}

// ---------------- Kernel 2: fused GEMM + dual softmax pooling ----------------
// FINAL: exact round-6 configuration -- the session's verified optimum
// (score 50.2 us). Structure: 128x128 block / 64x64 wave tiles; triple-
// buffered counted-vmcnt staging (depth-2 prefetch, vmcnt(4), one barrier
// per K-tile); XOR-swizzled glds staging (bank conflicts 4.7M -> 0.52M, r1);
// no-max softmax (r5, valid: cosine-sim inputs); DPP reductions on the VALU
// pipe (r6); mask pre-folded into H (r6).
// Post-r6 arcs, all measured and REVERTED:
//   r7  256x128 tile  (LDS -25%): 54.3 us -- occupancy 3->1.5 blocks/CU.
//   r8  B-direct 1-deep: 53.4 us -- uncovered L2 latency on B.
//   r9  B-direct 2-deep: 57.4 us -- per-iter 64-bit addr VALU.
//   r10 XCD swizzle: profiled dispatches 57-60 us (neutral-to-harmful).
//   r11/r12 in-register epilogue (conflicts -> 0 verified): 81/67 us --
//       acc tile spills to scratch (WRITE_SIZE 103/57 MB) once the epilogue
//       keeps all 64 acc values live; r6's streaming LDS epilogue does not.
// Structural floor of this template: no pipe >70% (LDS ~65-83k cyc/CU of
// 120k, VALU 38%, MFMA 27%, HBM 8%); residual is lockstep dependency
// overhead; every single-pipe reduction repaid in occupancy/latency/regs.
__global__ __launch_bounds__(256, 3) void score_kernel(
    const _Float16* __restrict__ H, float* __restrict__ out)
{
  // 3 GEMM buffers of 16 KB (sA 8K + sB 8K each) at 0/16384/32768.
  // Epilogue X (37120 B) overlays them after the K-loop.
  __shared__ __align__(16) char smem[49152];
  float*    X  = (float*)smem;

  const int tid  = threadIdx.x;
  const int w    = tid >> 6;
  const int lane = tid & 63;
  const int bn   = blockIdx.x;       // 0..31 -> 8 b's
  const int bm   = blockIdx.y;       // 0..63 -> 4 a's
  const int mBase = bm * 128;
  const int nBase = bn * 128;

  const char* gA = (const char*)(H + (size_t)mBase * D_DIM);
  const char* gB = (const char*)(H + (size_t)(A_N * T_TOK + nBase) * D_DIM);
  // Swizzled source (r1, verified): lane l stages row rbase+(l>>2), 16B chunk
  // ((l&3) ^ ((l>>3)&3)); LDS slot (row, c) holds global chunk c ^ ((row>>1)&3).
  const int rowoff = (lane >> 2) * 1024 + (((lane & 3) ^ ((lane >> 3) & 3)) * 16);
  const int rbase0 = w * 32;
  const int rbase1 = w * 32 + 16;

  char* bufA = smem;            // compute buffer (tile kt)
  char* bufB = smem + 16384;    // next (tile kt+1)
  char* bufC = smem + 32768;    // staging target (tile kt+2)

  // prologue: stage tile 0 -> bufA, tile 1 -> bufB (8 loads outstanding)
  async_copy16(gA + (size_t)rbase0 * 1024 + rowoff,        bufA + rbase0 * 64);
  async_copy16(gB + (size_t)rbase0 * 1024 + rowoff,        bufA + 8192 + rbase0 * 64);
  async_copy16(gA + (size_t)rbase1 * 1024 + rowoff,        bufA + rbase1 * 64);
  async_copy16(gB + (size_t)rbase1 * 1024 + rowoff,        bufA + 8192 + rbase1 * 64);
  async_copy16(gA + (size_t)rbase0 * 1024 + rowoff + 64,   bufB + rbase0 * 64);
  async_copy16(gB + (size_t)rbase0 * 1024 + rowoff + 64,   bufB + 8192 + rbase0 * 64);
  async_copy16(gA + (size_t)rbase1 * 1024 + rowoff + 64,   bufB + rbase1 * 64);
  async_copy16(gB + (size_t)rbase1 * 1024 + rowoff + 64,   bufB + 8192 + rbase1 * 64);

  floatx4 acc[4][4];
#pragma unroll
  for (int i = 0; i < 4; ++i)
#pragma unroll
    for (int j = 0; j < 4; ++j) acc[i][j] = {0.f, 0.f, 0.f, 0.f};

  const int colL = lane & 15;
  const int quad = lane >> 4;
  const int aRowBase = (w >> 1) * 64;
  const int bRowBase = (w & 1) * 64;
  // Read-side swizzle: row = base16 + colL -> (row>>1)&3 == (colL>>1)&3.
  const int quadS = (quad ^ ((colL >> 1) & 3)) * 8;

  // drain tile 0 only (keep tile 1's 4 loads in flight), then barrier
  asm volatile("s_waitcnt vmcnt(4)" ::: "memory");
  __builtin_amdgcn_s_barrier();

  for (int kt = 0; kt < 16; ++kt) {
    // stage tile kt+2 into bufC (stays in flight across this iteration's barrier)
    if (kt < 14) {
      const int kb = (kt + 2) * 64;
      async_copy16(gA + (size_t)rbase0 * 1024 + rowoff + kb, bufC + rbase0 * 64);
      async_copy16(gB + (size_t)rbase0 * 1024 + rowoff + kb, bufC + 8192 + rbase0 * 64);
      async_copy16(gA + (size_t)rbase1 * 1024 + rowoff + kb, bufC + rbase1 * 64);
      async_copy16(gB + (size_t)rbase1 * 1024 + rowoff + kb, bufC + 8192 + rbase1 * 64);
    }

    const _Float16* sA = (const _Float16*)bufA;
    const _Float16* sB = (const _Float16*)(bufA + 8192);
    half8 aF[4], bF[4];
#pragma unroll
    for (int i = 0; i < 4; ++i)
      aF[i] = *(const half8*)&sA[(aRowBase + i * 16 + colL) * 32 + quadS];
#pragma unroll
    for (int j = 0; j < 4; ++j)
      bF[j] = *(const half8*)&sB[(bRowBase + j * 16 + colL) * 32 + quadS];
#pragma unroll
    for (int i = 0; i < 4; ++i)
#pragma unroll
      for (int j = 0; j < 4; ++j)
        acc[i][j] = __builtin_amdgcn_mfma_f32_16x16x32_f16(aF[i], bF[j], acc[i][j], 0, 0, 0);

    // Retire tile kt+1's 4 loads (oldest), keep kt+2's in flight.
    // lgkmcnt(0): this wave's ds_reads must complete before the barrier,
    // since post-barrier glds writes target the rotated bufC = old bufA.
    if (kt < 14) asm volatile("s_waitcnt vmcnt(4) lgkmcnt(0)" ::: "memory");
    else         asm volatile("s_waitcnt vmcnt(0) lgkmcnt(0)" ::: "memory");
    __builtin_amdgcn_s_barrier();

    // rotate: bufA <- bufB (tile kt+1), bufB <- bufC (tile kt+2), bufC <- old bufA
    char* t = bufA; bufA = bufB; bufB = bufC; bufC = t;
  }

  // (mask already folded into H rows by norm_cast: masked logits are exact 0)

  // ---- epilogue: 2 iterations x 2 rounds ----
  const int pG = tid >> 5;          // pair (phases A/B)
  const int tA = tid & 31;          // t row (phase A)
  const int vB = (tid >> 1) & 15;   // v column (phase B)
  const int hB = tid & 1;           // t half (phase B)

  for (int it = 0; it < 2; ++it) {
    const int rjb = it * 2;
    // write 2 rounds: X[rr][p][v][t], t-contiguous float4 per (ip,ih)
#pragma unroll
    for (int rr = 0; rr < 2; ++rr)
#pragma unroll
      for (int ip = 0; ip < 2; ++ip)
#pragma unroll
        for (int ih = 0; ih < 2; ++ih)
          *(floatx4*)(X + rr * REP + (w * 2 + ip) * PS + colL * TS + ih * 16 + quad * 4)
              = acc[ip * 2 + ih][rjb + rr];
    __syncthreads();

    // ---------- phase A: t2v over v, then L2 over t ----------
    const float* pa = X + pG * PS + tA;
    float xa[16], xb[16];
#pragma unroll
    for (int v = 0; v < 16; ++v) { xa[v] = pa[v * TS]; xb[v] = pa[REP + v * TS]; }
    float sea, sxa, seb, sxb;
    expsum16(xa, sea, sxa);
    expsum16(xb, seb, sxb);
    const float tva = sxa * fast_rcp(sea);   // exact 0 for masked t
    const float tvb = sxb * fast_rcp(seb);

    const float va = (tva != 0.0f) ? tva : -1e30f;
    const float vb = (tvb != 0.0f) ? tvb : -1e30f;
    // level-2 over 32 t: no max; DPP group sum (valid in lane 31/63)
    float e2a = fast_exp2(va * K_LOG2E);     // -1e30 -> 0
    float e2b = fast_exp2(vb * K_LOG2E);
    const float s2a  = grp32_sum(e2a);
    const float sx2a = grp32_sum(va * e2a);  // (-1e30)*0 = -0
    const float s2b  = grp32_sum(e2b);
    const float sx2b = grp32_sum(vb * e2b);
    const float t2v_a = sx2a * fast_rcp(s2a);
    const float t2v_b = sx2b * fast_rcp(s2b);

    // ---------- phase B: v2t over t, then L2 over v ----------
    const float* pb = X + pG * PS + vB * TS + hB * 16;
    float ya[16], yb[16];
#pragma unroll
    for (int j4 = 0; j4 < 4; ++j4) {
      *(float4*)&ya[j4 * 4] = *(const float4*)(pb + j4 * 4);
      *(float4*)&yb[j4 * 4] = *(const float4*)(pb + REP + j4 * 4);
    }
#pragma unroll
    for (int i = 0; i < 16; ++i) {
      ya[i] = (ya[i] != 0.0f) ? ya[i] : -1e30f;
      yb[i] = (yb[i] != 0.0f) ? yb[i] : -1e30f;
    }
    float seBa, sxBa, seBb, sxBb;
    expsum16(ya, seBa, sxBa);   // masked: e=0, fmaf(-1e30, 0, s) = s
    expsum16(yb, seBb, sxBb);
    seBa = pair_sum(seBa);  sxBa = pair_sum(sxBa);   // t-halves (xor 1), all lanes
    seBb = pair_sum(seBb);  sxBb = pair_sum(sxBb);
    const float v2ta = sxBa * fast_rcp(seBa);
    const float v2tb = sxBb * fast_rcp(seBb);

    // level-2 over 16 v: values duplicated per lane-pair, so the 32-lane DPP
    // sum = 2x the v-sum -- factor cancels in the sx/s ratio.
    float e3a = fast_exp2(v2ta * K_LOG2E);
    float e3b = fast_exp2(v2tb * K_LOG2E);
    const float s3a  = grp32_sum(e3a);
    const float sx3a = grp32_sum(v2ta * e3a);
    const float s3b  = grp32_sum(e3b);
    const float sx3b = grp32_sum(v2tb * e3b);
    const float v2t_a = sx3a * fast_rcp(s3a);
    const float v2t_b = sx3b * fast_rcp(s3b);

    if ((tid & 31) == 31) {     // DPP group sums land in lane 31/63
      const int aL = (pG >> 2) * 2 + (pG & 1);
      const int bL = ((pG >> 1) & 1) * 4 + rjb;
      float* orow = out + (bm * 4 + aL) * B_N + bn * 8;
      orow[bL]     = 0.5f * (t2v_a + v2t_a);
      orow[bL + 1] = 0.5f * (t2v_b + v2t_b);
    }
    if (it == 0) __syncthreads();   // protect X before next iteration's writes
  }
}

extern "C" void kernel_launch(void* const* d_in, const int* in_sizes, int n_in,
                              void* d_out, int out_size, void* d_ws, size_t ws_size,
                              hipStream_t stream) {
  const float* text  = (const float*)d_in[0];
  const float* video = (const float*)d_in[1];
  const float* tmask = (const float*)d_in[2];
  float* out = (float*)d_out;
  _Float16* H = (_Float16*)d_ws;

  norm_cast_kernel<<<(A_N * T_TOK + B_N * V_FRM) / 16, 256, 0, stream>>>(text, video, tmask, H);
  score_kernel<<<dim3(B_N * V_FRM / 128, A_N * T_TOK / 128), 256, 0, stream>>>(H, out);
}